// Round 9
// baseline (908.574 us; speedup 1.0000x reference)
//
#include <hip/hip_runtime.h>

typedef _Float16 f16;
typedef _Float16 f16x4_t __attribute__((ext_vector_type(4)));
typedef _Float16 f16x8_t __attribute__((ext_vector_type(8)));
typedef float    f32x4_t __attribute__((ext_vector_type(4)));

#define HD 512          // h
#define CD 256          // c
#define ND 512          // N (codebook)
#define MROWS (4*24*2048)
#define WROWS 16        // rows per wave
#define TINV 10.0f      // 1/TEMP

// Fragment layout for MFMA B operands (validated R6): element (n,h) ->
// ((((n>>4)*16+(h>>5))*4+((h>>3)&3))*16+(n&15))*8+(h&7)
__device__ __forceinline__ int fragoff(int n, int h) {
  return ((((n >> 4) * 16 + (h >> 5)) * 4 + ((h >> 3) & 3)) * 16 + (n & 15)) * 8 + (h & 7);
}

// ---------------- prep: M = Wp @ Wq -> fp16 fragments; sb[n] = dot(Wp[n], bq)
__global__ void prep_M(const float* __restrict__ Wp, const float* __restrict__ Wq,
                       const float* __restrict__ bq, f16* __restrict__ MtF,
                       float* __restrict__ sb) {
  const int n = blockIdx.x;   // 0..511
  const int t = threadIdx.x;  // 0..255
  __shared__ float wpr[CD];
  __shared__ float sred[CD];
  wpr[t] = Wp[n * CD + t];
  __syncthreads();
  float a0 = 0.f, a1 = 0.f;
  #pragma unroll 8
  for (int c = 0; c < CD; ++c) {
    const float w = wpr[c];
    a0 = fmaf(w, Wq[c * HD + t], a0);
    a1 = fmaf(w, Wq[c * HD + t + 256], a1);
  }
  MtF[fragoff(n, t)]       = (f16)a0;
  MtF[fragoff(n, t + 256)] = (f16)a1;
  sred[t] = wpr[t] * bq[t];
  __syncthreads();
  for (int s = 128; s > 0; s >>= 1) {
    if (t < s) sred[t] += sred[t + s];
    __syncthreads();
  }
  if (t == 0) sb[n] = sred[0];
}

// ---------------- prep: WpF = GEMM3 B fragments (k-dim = n, cols = c), validated R6
__global__ void prep_WpF(const float* __restrict__ Wp, f16* __restrict__ WpF) {
  const int bx   = blockIdx.x;        // cf*16 + ks, 0..255
  const int lane = threadIdx.x;       // 0..63
  const int cf = bx >> 4, ks = bx & 15;
  const int q4 = lane >> 4, l16 = lane & 15;
  f16x8_t v;
  #pragma unroll
  for (int j = 0; j < 8; ++j)
    v[j] = (f16)Wp[(ks * 32 + q4 * 8 + j) * CD + cf * 16 + l16];
  *(f16x8_t*)(WpF + ((bx * 64) + lane) * 8) = v;
}

// ---------------- fused wave-private main: ZERO barriers.
// Each wave owns 16 rows + a private 16 KiB LDS buffer (H fp16 -> Q fp16 -> P fp32).
// Same-wave LDS program order replaces __syncthreads; softmax is 4 shfl_xor.
// Register model (R1-R8): (256,2) -> 2 waves/EU -> 256 total regs/wave.
// Live peak ~160 (acc 128 AGPR + misc) -> no spill (WRITE_SIZE is the tripwire).
// SWIZZLE RULE (R4): XOR the FULL byte offset (XOR-last).
__global__ __launch_bounds__(256, 2)
void fused_wave(const float* __restrict__ Hl, const f16* __restrict__ MtF,
                const f16* __restrict__ WpF, const float* __restrict__ sb,
                float* __restrict__ outP, float* __restrict__ outQ) {
  __shared__ __align__(16) char lds[4][WROWS * HD * 2];   // 4 x 16 KiB, wave-private
  const int tid  = threadIdx.x;
  const int lane = tid & 63;
  const int widx = tid >> 6;
  char* __restrict__ buf = lds[widx];
  const int q4  = lane >> 4;
  const int l16 = lane & 15;
  const long rbase = ((long)blockIdx.x * 4 + widx) * WROWS;

  // ---- stage H: 16 rows x 512 fp32 -> fp16 LDS (swizzled, coalesced 1KB/instr) ----
  {
    const float4* __restrict__ src = (const float4*)(Hl + rbase * HD);
    #pragma unroll
    for (int it = 0; it < 32; ++it) {
      const int f = it * 64 + lane;                 // float4 chunk, 128/row
      const float4 v = src[f];
      const int row = f >> 7;
      int byteoff = row * 1024 + ((f & 127) << 3);
      byteoff ^= (row & 7) << 4;
      f16x4_t h;
      h[0] = (f16)v.x; h[1] = (f16)v.y; h[2] = (f16)v.z; h[3] = (f16)v.w;
      *(f16x4_t*)(buf + byteoff) = h;
    }
  }

  // ---- GEMM1: scores[16][512] = H_f16 @ M^T ----
  f32x4_t acc[32];
  #pragma unroll
  for (int j = 0; j < 32; ++j)
    #pragma unroll
    for (int k = 0; k < 4; ++k) acc[j][k] = 0.f;

  {
    const char* __restrict__ mb = (const char*)MtF + lane * 16;
    for (int ks = 0; ks < 16; ++ks) {
      int aoff = l16 * 1024 + ks * 64 + q4 * 16;
      aoff ^= (l16 & 7) << 4;                        // XOR-last!
      const f16x8_t a = *(const f16x8_t*)(buf + aoff);
      #pragma unroll
      for (int nf = 0; nf < 32; ++nf) {
        const f16x8_t b = *(const f16x8_t*)(mb + (nf * 16 + ks) * 1024);
        acc[nf] = __builtin_amdgcn_mfma_f32_16x16x32_f16(a, b, acc[nf], 0, 0, 0);
      }
    }
  }

  // ---- softmax over N=512, direct exp (|logit| <~ 54 << 88), wave-local ----
  // thread holds rows rloc = q4*4+r, cols nf*16+l16; row spans 16 lanes (l16) x 32 nf
  float ps[4] = {0.f, 0.f, 0.f, 0.f};
  #pragma unroll
  for (int nf = 0; nf < 32; ++nf) {
    const float sbv = sb[nf * 16 + l16] * TINV;
    #pragma unroll
    for (int r = 0; r < 4; ++r) {
      const float e = __expf(fmaf(acc[nf][r], TINV, sbv));
      acc[nf][r] = e;
      ps[r] += e;
    }
  }
  #pragma unroll
  for (int st = 8; st >= 1; st >>= 1)
    #pragma unroll
    for (int r = 0; r < 4; ++r)
      ps[r] += __shfl_xor(ps[r], st, 64);           // within l16 group
  float rinv[4];
  #pragma unroll
  for (int r = 0; r < 4; ++r) rinv[r] = 1.0f / ps[r];

  // ---- Q fp16 scatter into private buf (H fully consumed; same-wave order) ----
  #pragma unroll
  for (int nf = 0; nf < 32; ++nf)
    #pragma unroll
    for (int r = 0; r < 4; ++r) {
      const int rloc = q4 * 4 + r;
      const int col  = nf * 16 + l16;
      int byteoff = rloc * 1024 + col * 2;
      byteoff ^= (rloc & 7) << 4;
      *(f16*)(buf + byteoff) = (f16)(acc[nf][r] * rinv[r]);
    }

  // ---- Q global store: coalesced float4 from LDS ----
  #pragma unroll
  for (int it = 0; it < 32; ++it) {
    const int f = it * 64 + lane;
    const int row = f >> 7;
    int byteoff = row * 1024 + ((f & 127) << 3);
    byteoff ^= (row & 7) << 4;
    const f16x4_t qv = *(const f16x4_t*)(buf + byteoff);
    float4 o;
    o.x = (float)qv[0]; o.y = (float)qv[1]; o.z = (float)qv[2]; o.w = (float)qv[3];
    *(float4*)(outQ + (rbase + row) * ND + ((f & 127) << 2)) = o;
  }

  // ---- GEMM3: P[16][256] = Q_f16 @ Wp ----
  f32x4_t acc2[16];
  #pragma unroll
  for (int j = 0; j < 16; ++j)
    #pragma unroll
    for (int k = 0; k < 4; ++k) acc2[j][k] = 0.f;

  {
    const char* __restrict__ wb = (const char*)WpF + lane * 16;
    for (int ks = 0; ks < 16; ++ks) {
      int aoff = l16 * 1024 + ks * 64 + q4 * 16;
      aoff ^= (l16 & 7) << 4;                        // XOR-last!
      const f16x8_t a = *(const f16x8_t*)(buf + aoff);
      #pragma unroll
      for (int nf = 0; nf < 16; ++nf) {
        const f16x8_t b = *(const f16x8_t*)(wb + (nf * 16 + ks) * 1024);
        acc2[nf] = __builtin_amdgcn_mfma_f32_16x16x32_f16(a, b, acc2[nf], 0, 0, 0);
      }
    }
  }

  // ---- P fp32 scatter into buf (Q reads done in program order), coalesced store ----
  #pragma unroll
  for (int nf = 0; nf < 16; ++nf)
    #pragma unroll
    for (int r = 0; r < 4; ++r) {
      const int rloc = q4 * 4 + r;
      const int col  = nf * 16 + l16;
      int byteoff = rloc * 1024 + col * 4;           // 16 rows x 256 f32, stride 1024B
      byteoff ^= (rloc & 7) << 4;
      *(float*)(buf + byteoff) = acc2[nf][r];
    }
  #pragma unroll
  for (int it = 0; it < 16; ++it) {
    const int f = it * 64 + lane;                    // float4 chunk, 64/row
    const int row = f >> 6;
    int byteoff = row * 1024 + ((f & 63) << 4);
    byteoff ^= (row & 7) << 4;
    const float4 pv = *(const float4*)(buf + byteoff);
    *(float4*)(outP + (rbase + row) * CD + ((f & 63) << 2)) = pv;
  }
}

extern "C" void kernel_launch(void* const* d_in, const int* in_sizes, int n_in,
                              void* d_out, int out_size, void* d_ws, size_t ws_size,
                              hipStream_t stream) {
  const float* Hl = (const float*)d_in[0];   // (B,T,V,H)
  const float* Wp = (const float*)d_in[1];   // (N,C)
  const float* Wq = (const float*)d_in[2];   // (C,H)
  const float* bq = (const float*)d_in[3];   // (C,)

  float* outP = (float*)d_out;                         // (M, C)
  float* outQ = (float*)d_out + (long)MROWS * CD;      // (M, N)

  f16*   MtF = (f16*)d_ws;                                        // 512 KiB
  f16*   WpF = (f16*)((char*)d_ws + ND * HD * 2);                 // 256 KiB
  float* sb  = (float*)((char*)d_ws + ND * HD * 2 + CD * ND * 2); // 2 KiB

  prep_M  <<<ND, CD, 0, stream>>>(Wp, Wq, bq, MtF, sb);
  prep_WpF<<<CD, 64, 0, stream>>>(Wp, WpF);
  fused_wave<<<(MROWS / WROWS) / 4, 256, 0, stream>>>(Hl, MtF, WpF, sb, outP, outQ);
}

// Round 10
// 584.016 us; speedup vs baseline: 1.5557x; 1.5557x over previous
//
#include <hip/hip_runtime.h>

typedef _Float16 f16;
typedef _Float16 f16x4_t __attribute__((ext_vector_type(4)));
typedef _Float16 f16x8_t __attribute__((ext_vector_type(8)));
typedef float    f32x4_t __attribute__((ext_vector_type(4)));

#define HD 512          // h
#define CD 256          // c
#define ND 512          // N (codebook)
#define MROWS (4*24*2048)
#define BM 64
#define NTHR 512
#define TINV 10.0f      // 1/TEMP

// Fragment layout for MFMA B operands (validated R6): element (n,h) ->
// ((((n>>4)*16+(h>>5))*4+((h>>3)&3))*16+(n&15))*8+(h&7)
__device__ __forceinline__ int fragoff(int n, int h) {
  return ((((n >> 4) * 16 + (h >> 5)) * 4 + ((h >> 3) & 3)) * 16 + (n & 15)) * 8 + (h & 7);
}

// ---------------- prep: M = Wp @ Wq -> fp16 fragments; sb[n] = dot(Wp[n], bq)
__global__ void prep_M(const float* __restrict__ Wp, const float* __restrict__ Wq,
                       const float* __restrict__ bq, f16* __restrict__ MtF,
                       float* __restrict__ sb) {
  const int n = blockIdx.x;   // 0..511
  const int t = threadIdx.x;  // 0..255
  __shared__ float wpr[CD];
  __shared__ float sred[CD];
  wpr[t] = Wp[n * CD + t];
  __syncthreads();
  float a0 = 0.f, a1 = 0.f;
  #pragma unroll 8
  for (int c = 0; c < CD; ++c) {
    const float w = wpr[c];
    a0 = fmaf(w, Wq[c * HD + t], a0);
    a1 = fmaf(w, Wq[c * HD + t + 256], a1);
  }
  MtF[fragoff(n, t)]       = (f16)a0;
  MtF[fragoff(n, t + 256)] = (f16)a1;
  sred[t] = wpr[t] * bq[t];
  __syncthreads();
  for (int s = 128; s > 0; s >>= 1) {
    if (t < s) sred[t] += sred[t + s];
    __syncthreads();
  }
  if (t == 0) sb[n] = sred[0];
}

// ---------------- prep: WpF = GEMM3 B fragments (k-dim = n, cols = c), validated R6
__global__ void prep_WpF(const float* __restrict__ Wp, f16* __restrict__ WpF) {
  const int bx   = blockIdx.x;        // cf*16 + ks, 0..255
  const int lane = threadIdx.x;       // 0..63
  const int cf = bx >> 4, ks = bx & 15;
  const int q4 = lane >> 4, l16 = lane & 15;
  f16x8_t v;
  #pragma unroll
  for (int j = 0; j < 8; ++j)
    v[j] = (f16)Wp[(ks * 32 + q4 * 8 + j) * CD + cf * 16 + l16];
  *(f16x8_t*)(WpF + ((bx * 64) + lane) * 8) = v;
}

// ---------------- fused main, 2 barriers total.
// GEMM1 A comes straight from global (fp32->fp16 in regs, fragment order) so HBM
// streaming overlaps MFMA + L2 B-loads inside the loop. Q and P store direct from
// regs; Q goes through LDS only for the GEMM3 transpose.
// Register model (R1-R9): (512,4) -> 4 waves/EU, 128 total regs/wave
// (64 arch VGPR + 64 AGPR acc, R6-measured). WRITE_SIZE is the spill tripwire.
// SWIZZLE RULE (R4): XOR the FULL byte offset (XOR-last).
__global__ __launch_bounds__(NTHR, 4)
void fused_main(const float* __restrict__ Hl, const f16* __restrict__ MtF,
                const f16* __restrict__ WpF, const float* __restrict__ sb,
                float* __restrict__ outP, float* __restrict__ outQ) {
  __shared__ __align__(16) char AQraw[BM * HD * 2];   // 64 KiB Q fp16, swizzled
  __shared__ float red[BM][4];

  const int tid  = threadIdx.x;
  const int lane = tid & 63;
  const int wid  = tid >> 6;         // 0..7
  const int wr   = wid >> 2;         // 0..1 (row half: 32 rows)
  const int wc   = wid & 3;          // 0..3 (col quarter)
  const int q4   = lane >> 4;        // 0..3
  const int l16  = lane & 15;
  const long rowbase = (long)blockIdx.x * BM;

  // ---- GEMM1: scores[64][512] = H @ M^T; A direct from global, B from MtF (L2) ----
  f32x4_t acc[2][8];
  #pragma unroll
  for (int i = 0; i < 2; ++i)
    #pragma unroll
    for (int j = 0; j < 8; ++j)
      #pragma unroll
      for (int k = 0; k < 4; ++k) acc[i][j][k] = 0.f;

  {
    const float* __restrict__ ha = Hl + (rowbase + wr * 32 + l16) * HD + q4 * 8;
    const char*  __restrict__ mb = (const char*)MtF + (wc * 8 * 16) * 1024 + lane * 16;
    for (int ks = 0; ks < 16; ++ks) {
      f16x8_t a[2];
      #pragma unroll
      for (int mf = 0; mf < 2; ++mf) {
        const float* p = ha + (long)mf * 16 * HD + ks * 32;
        const float4 v0 = *(const float4*)p;
        const float4 v1 = *(const float4*)(p + 4);
        f16x8_t t;
        t[0] = (f16)v0.x; t[1] = (f16)v0.y; t[2] = (f16)v0.z; t[3] = (f16)v0.w;
        t[4] = (f16)v1.x; t[5] = (f16)v1.y; t[6] = (f16)v1.z; t[7] = (f16)v1.w;
        a[mf] = t;
      }
      #pragma unroll
      for (int nf = 0; nf < 8; ++nf) {
        const f16x8_t b = *(const f16x8_t*)(mb + (nf * 16 + ks) * 1024);
        #pragma unroll
        for (int mf = 0; mf < 2; ++mf)
          acc[mf][nf] = __builtin_amdgcn_mfma_f32_16x16x32_f16(a[mf], b, acc[mf][nf], 0, 0, 0);
      }
    }
  }

  // ---- softmax over N=512, direct exp (|logit| <~ 54 << 88) ----
  // thread holds rows rloc = wr*32 + mf*16 + q4*4 + r, cols wc*128 + nf*16 + l16
  float sb10[8];
  #pragma unroll
  for (int nf = 0; nf < 8; ++nf) sb10[nf] = sb[wc * 128 + nf * 16 + l16] * TINV;

  float ps[2][4] = {{0.f,0.f,0.f,0.f},{0.f,0.f,0.f,0.f}};
  #pragma unroll
  for (int mf = 0; mf < 2; ++mf)
    #pragma unroll
    for (int nf = 0; nf < 8; ++nf)
      #pragma unroll
      for (int r = 0; r < 4; ++r) {
        const float e = __expf(fmaf(acc[mf][nf][r], TINV, sb10[nf]));
        acc[mf][nf][r] = e;
        ps[mf][r] += e;
      }
  #pragma unroll
  for (int st = 8; st >= 1; st >>= 1)
    #pragma unroll
    for (int mf = 0; mf < 2; ++mf)
      #pragma unroll
      for (int r = 0; r < 4; ++r)
        ps[mf][r] += __shfl_xor(ps[mf][r], st, 64);

  if (l16 == 0) {
    #pragma unroll
    for (int mf = 0; mf < 2; ++mf)
      #pragma unroll
      for (int r = 0; r < 4; ++r)
        red[wr * 32 + mf * 16 + q4 * 4 + r][wc] = ps[mf][r];
  }
  __syncthreads();                                   // barrier 1: partial-sum exchange

  float rinv[2][4];
  #pragma unroll
  for (int mf = 0; mf < 2; ++mf)
    #pragma unroll
    for (int r = 0; r < 4; ++r) {
      const int rloc = wr * 32 + mf * 16 + q4 * 4 + r;
      rinv[mf][r] = 1.0f / (red[rloc][0] + red[rloc][1] + red[rloc][2] + red[rloc][3]);
    }

  // ---- normalize: Q fp32 direct to global + Q fp16 into LDS (for transpose) ----
  #pragma unroll
  for (int mf = 0; mf < 2; ++mf)
    #pragma unroll
    for (int nf = 0; nf < 8; ++nf)
      #pragma unroll
      for (int r = 0; r < 4; ++r) {
        const int rloc = wr * 32 + mf * 16 + q4 * 4 + r;
        const int col  = wc * 128 + nf * 16 + l16;
        const float q = acc[mf][nf][r] * rinv[mf][r];
        outQ[(rowbase + rloc) * ND + col] = q;
        int byteoff = rloc * (ND * 2) + col * 2;
        byteoff ^= (rloc & 7) << 4;                  // XOR-last!
        *(f16*)(AQraw + byteoff) = (f16)q;
      }
  __syncthreads();                                   // barrier 2: Q ready for GEMM3

  // ---- GEMM3: P[64][256] = Q_f16 @ Wp; A from LDS, B from WpF (L2) ----
  f32x4_t acc2[2][4];
  #pragma unroll
  for (int i = 0; i < 2; ++i)
    #pragma unroll
    for (int j = 0; j < 4; ++j)
      #pragma unroll
      for (int k = 0; k < 4; ++k) acc2[i][j][k] = 0.f;

  {
    const char* __restrict__ wb = (const char*)WpF + (wc * 4 * 16) * 1024 + lane * 16;
    const int arow0 = wr * 32 + l16;
    for (int ks = 0; ks < 16; ++ks) {
      f16x8_t a[2];
      #pragma unroll
      for (int mf = 0; mf < 2; ++mf) {
        const int arow = arow0 + mf * 16;
        int byteoff = arow * (ND * 2) + ks * 64 + q4 * 16;
        byteoff ^= (arow & 7) << 4;                  // XOR-last!
        a[mf] = *(const f16x8_t*)(AQraw + byteoff);
      }
      #pragma unroll
      for (int nf = 0; nf < 4; ++nf) {
        const f16x8_t b = *(const f16x8_t*)(wb + (nf * 16 + ks) * 1024);
        #pragma unroll
        for (int mf = 0; mf < 2; ++mf)
          acc2[mf][nf] = __builtin_amdgcn_mfma_f32_16x16x32_f16(a[mf], b, acc2[mf][nf], 0, 0, 0);
      }
    }
  }

  // ---- P fp32 direct stores from regs (64B segments) ----
  #pragma unroll
  for (int mf = 0; mf < 2; ++mf)
    #pragma unroll
    for (int nf = 0; nf < 4; ++nf)
      #pragma unroll
      for (int r = 0; r < 4; ++r) {
        const long row = rowbase + wr * 32 + mf * 16 + q4 * 4 + r;
        const int  col = wc * 64 + nf * 16 + l16;
        outP[row * CD + col] = acc2[mf][nf][r];
      }
}

extern "C" void kernel_launch(void* const* d_in, const int* in_sizes, int n_in,
                              void* d_out, int out_size, void* d_ws, size_t ws_size,
                              hipStream_t stream) {
  const float* Hl = (const float*)d_in[0];   // (B,T,V,H)
  const float* Wp = (const float*)d_in[1];   // (N,C)
  const float* Wq = (const float*)d_in[2];   // (C,H)
  const float* bq = (const float*)d_in[3];   // (C,)

  float* outP = (float*)d_out;                         // (M, C)
  float* outQ = (float*)d_out + (long)MROWS * CD;      // (M, N)

  f16*   MtF = (f16*)d_ws;                                        // 512 KiB
  f16*   WpF = (f16*)((char*)d_ws + ND * HD * 2);                 // 256 KiB
  float* sb  = (float*)((char*)d_ws + ND * HD * 2 + CD * ND * 2); // 2 KiB

  prep_M  <<<ND, CD, 0, stream>>>(Wp, Wq, bq, MtF, sb);
  prep_WpF<<<CD, 64, 0, stream>>>(Wp, WpF);
  fused_main<<<MROWS / BM, NTHR, 0, stream>>>(Hl, MtF, WpF, sb, outP, outQ);
}

// Round 11
// 431.321 us; speedup vs baseline: 2.1065x; 1.3540x over previous
//
#include <hip/hip_runtime.h>

typedef _Float16 f16;
typedef _Float16 f16x4_t __attribute__((ext_vector_type(4)));
typedef _Float16 f16x8_t __attribute__((ext_vector_type(8)));
typedef float    f32x4_t __attribute__((ext_vector_type(4)));

#define HD 512          // h
#define CD 256          // c
#define ND 512          // N (codebook)
#define MROWS (4*24*2048)
#define BM 64
#define NTHR 512
#define TINV 10.0f      // 1/TEMP

// Fragment layout for MFMA B operands (validated R6): element (n,h) ->
// ((((n>>4)*16+(h>>5))*4+((h>>3)&3))*16+(n&15))*8+(h&7)
__device__ __forceinline__ int fragoff(int n, int h) {
  return ((((n >> 4) * 16 + (h >> 5)) * 4 + ((h >> 3) & 3)) * 16 + (n & 15)) * 8 + (h & 7);
}

// ---------------- prep: M = Wp @ Wq -> fp16 fragments; sb[n] = dot(Wp[n], bq)
__global__ void prep_M(const float* __restrict__ Wp, const float* __restrict__ Wq,
                       const float* __restrict__ bq, f16* __restrict__ MtF,
                       float* __restrict__ sb) {
  const int n = blockIdx.x;   // 0..511
  const int t = threadIdx.x;  // 0..255
  __shared__ float wpr[CD];
  __shared__ float sred[CD];
  wpr[t] = Wp[n * CD + t];
  __syncthreads();
  float a0 = 0.f, a1 = 0.f;
  #pragma unroll 8
  for (int c = 0; c < CD; ++c) {
    const float w = wpr[c];
    a0 = fmaf(w, Wq[c * HD + t], a0);
    a1 = fmaf(w, Wq[c * HD + t + 256], a1);
  }
  MtF[fragoff(n, t)]       = (f16)a0;
  MtF[fragoff(n, t + 256)] = (f16)a1;
  sred[t] = wpr[t] * bq[t];
  __syncthreads();
  for (int s = 128; s > 0; s >>= 1) {
    if (t < s) sred[t] += sred[t + s];
    __syncthreads();
  }
  if (t == 0) sb[n] = sred[0];
}

// ---------------- prep: WpF = GEMM3 B fragments (k-dim = n, cols = c), validated R6
__global__ void prep_WpF(const float* __restrict__ Wp, f16* __restrict__ WpF) {
  const int bx   = blockIdx.x;        // cf*16 + ks, 0..255
  const int lane = threadIdx.x;       // 0..63
  const int cf = bx >> 4, ks = bx & 15;
  const int q4 = lane >> 4, l16 = lane & 15;
  f16x8_t v;
  #pragma unroll
  for (int j = 0; j < 8; ++j)
    v[j] = (f16)Wp[(ks * 32 + q4 * 8 + j) * CD + cf * 16 + l16];
  *(f16x8_t*)(WpF + ((bx * 64) + lane) * 8) = v;
}

// ---------------- fused main, 64x64 wave tiles.
// Each of 8 waves: 64 rows x 64 cols (GEMM1) / 64 rows x 32 cols (GEMM3).
// Halves per-WG L2 B-traffic vs 32x128 tiles and doubles MFMA:B-load ratio
// (4 loads : 16 MFMA per ks). A from LDS (R6 staging); Q,P store direct from regs.
// Register model: (512,4) -> 128 total regs/wave = 64 arch VGPR + 64 AGPR acc.
// WRITE_SIZE is the spill tripwire. SWIZZLE RULE (R4): XOR the FULL offset.
__global__ __launch_bounds__(NTHR, 4)
void fused_main(const float* __restrict__ Hl, const f16* __restrict__ MtF,
                const f16* __restrict__ WpF, const float* __restrict__ sb,
                float* __restrict__ outP, float* __restrict__ outQ) {
  __shared__ __align__(16) char AQraw[BM * HD * 2];   // 64 KiB: H fp16 -> Q fp16
  __shared__ float red[BM][8];
  __shared__ float rstat[BM];

  const int tid  = threadIdx.x;
  const int lane = tid & 63;
  const int wid  = tid >> 6;         // 0..7 = 64-col slice (GEMM1) / 32-col slice (GEMM3)
  const int q4   = lane >> 4;        // 0..3
  const int l16  = lane & 15;
  const long rowbase = (long)blockIdx.x * BM;

  // ---- stage H: 64 rows x 512 fp32 -> fp16 LDS (swizzled) ----
  {
    const float4* __restrict__ src = (const float4*)(Hl + rowbase * HD);
    #pragma unroll
    for (int it = 0; it < (BM * HD / 4) / NTHR; ++it) {   // 16 iters
      const int f = it * NTHR + tid;
      const float4 v = src[f];
      const int row = f >> 7;
      int byteoff = row * (HD * 2) + ((f & 127) << 3);
      byteoff ^= (row & 7) << 4;
      f16x4_t h;
      h[0] = (f16)v.x; h[1] = (f16)v.y; h[2] = (f16)v.z; h[3] = (f16)v.w;
      *(f16x4_t*)(AQraw + byteoff) = h;
    }
  }
  __syncthreads();                                   // barrier 1

  // ---- GEMM1: wave tile 64 rows x 64 cols; B from MtF (L2) ----
  f32x4_t acc[4][4];
  #pragma unroll
  for (int i = 0; i < 4; ++i)
    #pragma unroll
    for (int j = 0; j < 4; ++j)
      #pragma unroll
      for (int k = 0; k < 4; ++k) acc[i][j][k] = 0.f;

  {
    const char* __restrict__ mb = (const char*)MtF + (wid * 4 * 16) * 1024 + lane * 16;
    for (int ks = 0; ks < 16; ++ks) {
      f16x8_t a[4];
      #pragma unroll
      for (int mf = 0; mf < 4; ++mf) {
        const int arow = mf * 16 + l16;
        int byteoff = arow * (HD * 2) + ks * 64 + q4 * 16;
        byteoff ^= (arow & 7) << 4;                  // XOR-last!
        a[mf] = *(const f16x8_t*)(AQraw + byteoff);
      }
      #pragma unroll
      for (int nf = 0; nf < 4; ++nf) {
        const f16x8_t b = *(const f16x8_t*)(mb + (nf * 16 + ks) * 1024);
        #pragma unroll
        for (int mf = 0; mf < 4; ++mf)
          acc[mf][nf] = __builtin_amdgcn_mfma_f32_16x16x32_f16(a[mf], b, acc[mf][nf], 0, 0, 0);
      }
    }
  }

  // ---- softmax over N=512, direct exp (|logit| <~ 54 << 88) ----
  // thread rows: mf*16 + q4*4 + r; cols: wid*64 + nf*16 + l16
  float sb10[4];
  #pragma unroll
  for (int nf = 0; nf < 4; ++nf) sb10[nf] = sb[wid * 64 + nf * 16 + l16] * TINV;

  float ps[4][4];
  #pragma unroll
  for (int mf = 0; mf < 4; ++mf)
    #pragma unroll
    for (int r = 0; r < 4; ++r) ps[mf][r] = 0.f;
  #pragma unroll
  for (int mf = 0; mf < 4; ++mf)
    #pragma unroll
    for (int nf = 0; nf < 4; ++nf)
      #pragma unroll
      for (int r = 0; r < 4; ++r) {
        const float e = __expf(fmaf(acc[mf][nf][r], TINV, sb10[nf]));
        acc[mf][nf][r] = e;
        ps[mf][r] += e;
      }
  #pragma unroll
  for (int st = 8; st >= 1; st >>= 1)
    #pragma unroll
    for (int mf = 0; mf < 4; ++mf)
      #pragma unroll
      for (int r = 0; r < 4; ++r)
        ps[mf][r] += __shfl_xor(ps[mf][r], st, 64);

  if (l16 == 0) {
    #pragma unroll
    for (int mf = 0; mf < 4; ++mf)
      #pragma unroll
      for (int r = 0; r < 4; ++r)
        red[mf * 16 + q4 * 4 + r][wid] = ps[mf][r];
  }
  __syncthreads();                                   // barrier 2
  if (tid < BM) {
    const float* rr = red[tid];
    rstat[tid] = 1.0f / (rr[0] + rr[1] + rr[2] + rr[3] + rr[4] + rr[5] + rr[6] + rr[7]);
  }
  __syncthreads();                                   // barrier 3

  // ---- normalize: Q fp32 direct to global + Q fp16 into LDS (transpose for GEMM3) ----
  #pragma unroll
  for (int mf = 0; mf < 4; ++mf) {
    float rinv[4];
    #pragma unroll
    for (int r = 0; r < 4; ++r)
      rinv[r] = rstat[mf * 16 + q4 * 4 + r];
    #pragma unroll
    for (int nf = 0; nf < 4; ++nf)
      #pragma unroll
      for (int r = 0; r < 4; ++r) {
        const int rloc = mf * 16 + q4 * 4 + r;
        const int col  = wid * 64 + nf * 16 + l16;
        const float q = acc[mf][nf][r] * rinv[r];
        outQ[(rowbase + rloc) * ND + col] = q;
        int byteoff = rloc * (ND * 2) + col * 2;
        byteoff ^= (rloc & 7) << 4;                  // XOR-last!
        *(f16*)(AQraw + byteoff) = (f16)q;
      }
  }
  __syncthreads();                                   // barrier 4: Q ready

  // ---- GEMM3: wave tile 64 rows x 32 cols; A from LDS, B from WpF (L2) ----
  f32x4_t acc2[4][2];
  #pragma unroll
  for (int i = 0; i < 4; ++i)
    #pragma unroll
    for (int j = 0; j < 2; ++j)
      #pragma unroll
      for (int k = 0; k < 4; ++k) acc2[i][j][k] = 0.f;

  {
    const char* __restrict__ wb = (const char*)WpF + (wid * 2 * 16) * 1024 + lane * 16;
    for (int ks = 0; ks < 16; ++ks) {
      f16x8_t a[4];
      #pragma unroll
      for (int mf = 0; mf < 4; ++mf) {
        const int arow = mf * 16 + l16;
        int byteoff = arow * (ND * 2) + ks * 64 + q4 * 16;
        byteoff ^= (arow & 7) << 4;                  // XOR-last!
        a[mf] = *(const f16x8_t*)(AQraw + byteoff);
      }
      #pragma unroll
      for (int nf = 0; nf < 2; ++nf) {
        const f16x8_t b = *(const f16x8_t*)(wb + (nf * 16 + ks) * 1024);
        #pragma unroll
        for (int mf = 0; mf < 4; ++mf)
          acc2[mf][nf] = __builtin_amdgcn_mfma_f32_16x16x32_f16(a[mf], b, acc2[mf][nf], 0, 0, 0);
      }
    }
  }

  // ---- P fp32 direct stores from regs (64B segments) ----
  #pragma unroll
  for (int mf = 0; mf < 4; ++mf)
    #pragma unroll
    for (int nf = 0; nf < 2; ++nf)
      #pragma unroll
      for (int r = 0; r < 4; ++r) {
        const long row = rowbase + mf * 16 + q4 * 4 + r;
        const int  col = wid * 32 + nf * 16 + l16;
        outP[row * CD + col] = acc2[mf][nf][r];
      }
}

extern "C" void kernel_launch(void* const* d_in, const int* in_sizes, int n_in,
                              void* d_out, int out_size, void* d_ws, size_t ws_size,
                              hipStream_t stream) {
  const float* Hl = (const float*)d_in[0];   // (B,T,V,H)
  const float* Wp = (const float*)d_in[1];   // (N,C)
  const float* Wq = (const float*)d_in[2];   // (C,H)
  const float* bq = (const float*)d_in[3];   // (C,)

  float* outP = (float*)d_out;                         // (M, C)
  float* outQ = (float*)d_out + (long)MROWS * CD;      // (M, N)

  f16*   MtF = (f16*)d_ws;                                        // 512 KiB
  f16*   WpF = (f16*)((char*)d_ws + ND * HD * 2);                 // 256 KiB
  float* sb  = (float*)((char*)d_ws + ND * HD * 2 + CD * ND * 2); // 2 KiB

  prep_M  <<<ND, CD, 0, stream>>>(Wp, Wq, bq, MtF, sb);
  prep_WpF<<<CD, 64, 0, stream>>>(Wp, WpF);
  fused_main<<<MROWS / BM, NTHR, 0, stream>>>(Hl, MtF, WpF, sb, outP, outQ);
}